// Round 7
// baseline (234.686 us; speedup 1.0000x reference)
//
#include <hip/hip_runtime.h>
#include <hip/hip_bf16.h>

#define NPC 18432        // per-channel element count for BN
#define PDIM 98          // padded spatial dim
#define PELEM (2*98*98*64)
#define PSTRIDE 2312     // bf16 units per pos in prL: 4*72*8=2304 +8 pad
#define HALO_F 49664     // 2b * 388 halo-pos * 64 ch

typedef __attribute__((ext_vector_type(2))) float f32x2;

__device__ __forceinline__ f32x2 fma2(f32x2 a, f32x2 b, f32x2 c) {
#if __has_builtin(__builtin_elementwise_fma)
    return __builtin_elementwise_fma(a, b, c);
#else
    return f32x2{fmaf(a.x, b.x, c.x), fmaf(a.y, b.y, c.y)};
#endif
}
__device__ __forceinline__ float dot8v(f32x2 a0, f32x2 a1, f32x2 a2, f32x2 a3,
                                       f32x2 b0, f32x2 b1, f32x2 b2, f32x2 b3) {
    f32x2 acc = a0 * b0;
    acc = fma2(a1, b1, acc);
    acc = fma2(a2, b2, acc);
    acc = fma2(a3, b3, acc);
    return acc.x + acc.y;
}

template <int CTRL>
__device__ __forceinline__ float dpp_add(float x) {
    int y = __builtin_amdgcn_update_dpp(0, __float_as_int(x), CTRL, 0xF, 0xF, true);
    return x + __int_as_float(y);
}
__device__ __forceinline__ float red_lo(float x) {   // xor 1,2,4
    x = dpp_add<0xB1>(x);
    x = dpp_add<0x4E>(x);
    x = dpp_add<0x141>(x);
    return x;
}
__device__ __forceinline__ float red_hi(float x) {   // xor 8,16,32
    x = dpp_add<0x128>(x);
    x += __shfl_xor(x, 16);
    x += __shfl_xor(x, 32);
    return x;
}

__device__ __forceinline__ int detect_is32(const unsigned short* __restrict__ w1u) {
    int lane = threadIdx.x & 63;
    int bad = 0;
    #pragma unroll
    for (int i = 0; i < 16; ++i) {
        unsigned short u = (unsigned short)(w1u[lane + i * 64] & 0x7FFF);
        bad |= (u >= 0x42C8);   // bf16 |v| >= 100 or NaN/Inf
    }
    return (__ballot(bad) != 0ULL) ? 1 : 0;
}

__device__ __forceinline__ float load_in(const void* p, int idx, int is32) {
    return is32 ? ((const float*)p)[idx]
                : __bfloat162float(((const __hip_bfloat16*)p)[idx]);
}

__device__ __forceinline__ float lo16(unsigned v) { return __int_as_float((int)(v << 16)); }
__device__ __forceinline__ float hi16(unsigned v) { return __int_as_float((int)(v & 0xFFFF0000u)); }

// halo position r in [0,388) -> (yy,xx) on the 98x98 border
__device__ __forceinline__ void halo_pos(int r, int& yy, int& xx) {
    if (r < 98)       { yy = 0;            xx = r; }
    else if (r < 196) { yy = 97;           xx = r - 98; }
    else if (r < 292) { yy = r - 196 + 1;  xx = 0; }
    else              { yy = r - 292 + 1;  xx = 97; }
}

// ---------------------------------------------------------------------------
// prep: 0..575 x-transpose into padded xt; 576..863 weight transpose;
// 864..883 zero xt halo; 884 zero stats+bias1.
// ---------------------------------------------------------------------------
__launch_bounds__(256)
__global__ void prep_kernel(const void* __restrict__ x,
                            const void* __restrict__ w1, const void* __restrict__ w2,
                            float* __restrict__ xt,
                            float* __restrict__ wT1, float* __restrict__ wT2,
                            float* __restrict__ statz, float* __restrict__ bias1) {
    __shared__ float tile[64 * 33];
    const int bid = blockIdx.x;
    if (bid < 576) {
        const int is32 = detect_is32((const unsigned short*)w1);
        int xb = bid % 3, y = (bid / 3) % 96, b = bid / 288;
        int x0 = xb * 32;
        for (int e = threadIdx.x; e < 2048; e += 256) {
            int xl = e & 31, c = e >> 5;
            tile[c * 33 + xl] = load_in(x, ((b * 64 + c) * 96 + y) * 96 + x0 + xl, is32);
        }
        __syncthreads();
        for (int f = threadIdx.x; f < 2048; f += 256) {
            int c = f & 63, xl = f >> 6;
            xt[((b * PDIM + y + 1) * PDIM + x0 + 1 + xl) * 64 + c] = tile[c * 33 + xl];
        }
    } else if (bid < 864) {
        const int is32 = detect_is32((const unsigned short*)w1);
        int t = (bid - 576) * 256 + threadIdx.x;   // 0..73727
        const void* w = (t < 36864) ? w1 : w2;
        float* wT = (t < 36864) ? wT1 : wT2;
        int e = t % 36864;
        int l  = e & 7;
        int m  = (e >> 3) & 7;
        int k  = (e >> 6) % 9;
        int oi = e / 576;
        int dy = k / 3, dx = k % 3;
        int src = (((oi * 3 + dy) * 3 + dx) * 8 + l) * 8 + m;
        wT[e] = load_in(w, src, is32);
    } else if (bid < 884) {
        for (int f = (bid - 864) * 256 + threadIdx.x; f < HALO_F; f += 20 * 256) {
            int b = f / (HALO_F / 2);
            int rr = f % (HALO_F / 2);
            int pos = rr >> 6, c = rr & 63;
            int yy, xx;
            halo_pos(pos, yy, xx);
            xt[((b * PDIM + yy) * PDIM + xx) * 64 + c] = 0.f;
        }
    } else {
        for (int e = threadIdx.x; e < 2048; e += 256) statz[e] = 0.f;
        for (int e = threadIdx.x; e < 4608; e += 256) bias1[e] = 0.f;
    }
}

// ---------------------------------------------------------------------------
// fold: after caps1. Computes sc1/sh1 from statL1; scales wT2 in-place;
// builds bias2 from raw w2; fills yt1 halo with -sh1/sc1 (so OOB taps
// contribute exactly 0 through the folded path).
// ---------------------------------------------------------------------------
__launch_bounds__(256)
__global__ void fold_kernel(const float* __restrict__ statL,
                            const void* __restrict__ gamma, const void* __restrict__ beta,
                            const void* __restrict__ w1,    // for dtype detect
                            const void* __restrict__ w2,    // raw layer-2 weights
                            float* __restrict__ wT2,
                            float* __restrict__ bias2,
                            float* __restrict__ yt1) {
    __shared__ float scL[64], shL[64], hvL[64];
    const int is32 = detect_is32((const unsigned short*)w1);
    if (threadIdx.x < 64) {
        int c = threadIdx.x;
        float s = 0.f, ss = 0.f;
        #pragma unroll
        for (int cp = 0; cp < 8; ++cp) {
            s  += statL[cp * 128 + c];
            ss += statL[cp * 128 + 64 + c];
        }
        float mean = s * (1.f / (float)NPC);
        float var  = fmaxf(ss * (1.f / (float)NPC) - mean * mean, 0.f);
        float inv  = rsqrtf(var + 1e-5f);
        float g = load_in(gamma, c, is32) * inv;
        float h = load_in(beta, c, is32) - mean * g;
        scL[c] = g;
        shL[c] = h;
        hvL[c] = -h / g;
    }
    __syncthreads();

    const int bid = blockIdx.x;
    if (bid < 144) {
        int e = bid * 256 + threadIdx.x;    // < 36864
        int l = e & 7, jj = (e / 576) & 7;
        wT2[e] = wT2[e] * scL[jj * 8 + l];
    } else if (bid < 162) {
        int idx = (bid - 144) * 256 + threadIdx.x;
        if (idx < 4608) {
            int m = idx & 7, t = (idx >> 3) % 9, jj = (idx / 72) & 7, o = idx / 576;
            int dy = t / 3, dx = t % 3;
            float s = 0.f;
            #pragma unroll
            for (int l = 0; l < 8; ++l) {
                int src = ((((o * 8 + jj) * 3 + dy) * 3 + dx) * 8 + l) * 8 + m;
                s = fmaf(shL[jj * 8 + l], load_in(w2, src, is32), s);
            }
            bias2[idx] = s;
        }
    } else {
        for (int f = (bid - 162) * 256 + threadIdx.x; f < HALO_F; f += 32 * 256) {
            int b = f / (HALO_F / 2);
            int rr = f % (HALO_F / 2);
            int pos = rr >> 6, c = rr & 63;
            int yy, xx;
            halo_pos(pos, yy, xx);
            yt1[((b * PDIM + yy) * PDIM + xx) * 64 + c] = hvL[c];
        }
    }
}

// ---------------------------------------------------------------------------
// Fused capsule conv + routing + BN-stat partials (both layers identical:
// BN folded into weights/bias upstream; zero-effect halo handles padding).
// Block = 256 = 4 waves; wave ol -> o = oh*4+ol, 8 x-positions.
// Phase 1 (lane=jj*8+m): direct-global row reads (jj-broadcast, L1-hot).
// Phase 2 (lane=p*8+i):  register priors, m in-lane, DPP i-reduce.
// ---------------------------------------------------------------------------
__launch_bounds__(256, 4)
__global__ void caps_kernel(const float* __restrict__ in,     // [b][98][98][64] padded
                            const float* __restrict__ wT,
                            const float* __restrict__ bias,   // [o][jj][t][m]
                            float* __restrict__ yout,         // [b][98][98][64] padded
                            float* __restrict__ statL) {      // [8 copies][128]
    __shared__ __align__(16) __hip_bfloat16 prL[8 * PSTRIDE]; // [pos][(ol*72+i*9+k)*8+m]
    __shared__ float omI[8 * 32];                             // [pos][ol*8+m]

    const int bx  = blockIdx.x;
    const int gx0 = (bx >> 1) * 8;
    const int oh  = bx & 1;
    const int y   = blockIdx.y;
    const int b   = blockIdx.z;
    const int tid = threadIdx.x;

    const int ol   = tid >> 6;
    const int lane = tid & 63;

    // ================= Phase 1: priors (lane = jj*8 + m) =================
    {
        const int m  = lane & 7;
        const int jj = lane >> 3;
        const int o  = oh * 4 + ol;
        const float* wb = wT + o * 4608 + jj * 576 + m * 8;
        __hip_bfloat16* prw = &prL[(ol * 72 + jj * 9) * 8 + m];

        float bs[9];
        #pragma unroll
        for (int t = 0; t < 9; ++t) bs[t] = bias[(o * 8 + jj) * 72 + t * 8 + m];

        float s[8] = {0.f, 0.f, 0.f, 0.f, 0.f, 0.f, 0.f, 0.f};
        #pragma unroll
        for (int dy = 0; dy < 3; ++dy) {
            const float* rowp = in + ((b * PDIM + y + dy) * PDIM + gx0) * 64 + jj * 8;
            f32x2 row2[40];
            #pragma unroll
            for (int col = 0; col < 10; ++col) {
                float4 fa = *(const float4*)(rowp + col * 64);
                float4 fb = *(const float4*)(rowp + col * 64 + 4);
                row2[col * 4 + 0] = f32x2{fa.x, fa.y};
                row2[col * 4 + 1] = f32x2{fa.z, fa.w};
                row2[col * 4 + 2] = f32x2{fb.x, fb.y};
                row2[col * 4 + 3] = f32x2{fb.z, fb.w};
            }
            #pragma unroll
            for (int dx = 0; dx < 3; ++dx) {
                const int t = dy * 3 + dx;
                float4 wa = *(const float4*)(wb + t * 64);
                float4 wc = *(const float4*)(wb + t * 64 + 4);
                f32x2 w0{wa.x, wa.y}, w1v{wa.z, wa.w}, w2v{wc.x, wc.y}, w3v{wc.z, wc.w};
                #pragma unroll
                for (int p = 0; p < 8; ++p) {
                    const int base = (dx + p) * 4;
                    float a = dot8v(row2[base], row2[base + 1], row2[base + 2], row2[base + 3],
                                    w0, w1v, w2v, w3v) + bs[t];
                    s[p] += a;
                    prw[p * PSTRIDE + t * 8] = __float2bfloat16(a);
                }
            }
        }
        #pragma unroll
        for (int p = 0; p < 8; ++p) {
            float v = red_hi(s[p]);
            if (jj == 0) omI[p * 32 + ol * 8 + m] = v * (1.f / 72.f);
        }
    }
    // No barrier: each wave's prL/omI region is produced & consumed by itself.

    // ================= Phase 2: routing (lane = p*8 + i) =================
    const int i = lane & 7;
    const int p = lane >> 3;
    const __hip_bfloat16* pbase = &prL[p * PSTRIDE + (ol * 72 + i * 9) * 8];

    uint4 u[9];
    #pragma unroll
    for (int k = 0; k < 9; ++k) u[k] = *(const uint4*)(pbase + k * 8);

    f32x2 fr[36];
    float n1[9];
    #pragma unroll
    for (int k = 0; k < 9; ++k) {
        fr[4 * k + 0] = f32x2{lo16(u[k].x), hi16(u[k].x)};
        fr[4 * k + 1] = f32x2{lo16(u[k].y), hi16(u[k].y)};
        fr[4 * k + 2] = f32x2{lo16(u[k].z), hi16(u[k].z)};
        fr[4 * k + 3] = f32x2{lo16(u[k].w), hi16(u[k].w)};
        n1[k] = dot8v(fr[4 * k], fr[4 * k + 1], fr[4 * k + 2], fr[4 * k + 3],
                      fr[4 * k], fr[4 * k + 1], fr[4 * k + 2], fr[4 * k + 3]);
    }

    f32x2 om2[4];
    {
        const float* ob = &omI[p * 32 + ol * 8];
        float4 o0 = *(const float4*)ob;
        float4 o1 = *(const float4*)(ob + 4);
        om2[0] = f32x2{o0.x, o0.y}; om2[1] = f32x2{o0.z, o0.w};
        om2[2] = f32x2{o1.x, o1.y}; om2[3] = f32x2{o1.z, o1.w};
    }
    float n2 = dot8v(om2[0], om2[1], om2[2], om2[3], om2[0], om2[1], om2[2], om2[3]);

    #pragma unroll
    for (int it = 0; it < 3; ++it) {
        float se = 0.f;
        f32x2 acc2[4] = {f32x2{0.f, 0.f}, f32x2{0.f, 0.f}, f32x2{0.f, 0.f}, f32x2{0.f, 0.f}};
        #pragma unroll
        for (int k = 0; k < 9; ++k) {
            float d = dot8v(fr[4 * k], fr[4 * k + 1], fr[4 * k + 2], fr[4 * k + 3],
                            om2[0], om2[1], om2[2], om2[3]);
            float denom = fmaxf(n1[k] + n2 - d, 1e-8f);
            float e = __expf(d * __builtin_amdgcn_rcpf(denom));
            se += e;
            f32x2 ev{e, e};
            acc2[0] = fma2(ev, fr[4 * k + 0], acc2[0]);
            acc2[1] = fma2(ev, fr[4 * k + 1], acc2[1]);
            acc2[2] = fma2(ev, fr[4 * k + 2], acc2[2]);
            acc2[3] = fma2(ev, fr[4 * k + 3], acc2[3]);
        }
        se = red_lo(se);
        #pragma unroll
        for (int q = 0; q < 4; ++q) {
            acc2[q].x = red_lo(acc2[q].x);
            acc2[q].y = red_lo(acc2[q].y);
        }
        float inv = __builtin_amdgcn_rcpf(se);
        f32x2 iv{inv, inv};
        #pragma unroll
        for (int q = 0; q < 4; ++q) om2[q] = acc2[q] * iv;
        n2 = dot8v(om2[0], om2[1], om2[2], om2[3], om2[0], om2[1], om2[2], om2[3]);
    }

    if (i == 0) {
        float4 o0 = {om2[0].x, om2[0].y, om2[1].x, om2[1].y};
        float4 o1 = {om2[2].x, om2[2].y, om2[3].x, om2[3].y};
        float* dst = &yout[((b * PDIM + y + 1) * PDIM + gx0 + 1 + p) * 64 + (oh * 4 + ol) * 8];
        *(float4*)dst = o0;
        *(float4*)(dst + 4) = o1;
        *(float4*)&omI[p * 32 + ol * 8] = o0;
        *(float4*)&omI[p * 32 + ol * 8 + 4] = o1;
    }
    __syncthreads();

    // ---- BN stat partials: 32 channels (oh half), sum over 8 positions ----
    if (tid < 64) {
        int c32 = tid & 31, sel = tid >> 5;
        float v = 0.f;
        #pragma unroll
        for (int pp = 0; pp < 8; ++pp) {
            float uu = omI[pp * 32 + c32];
            v += sel ? uu * uu : uu;
        }
        int cp = (blockIdx.x + blockIdx.y * 3 + blockIdx.z) & 7;
        atomicAdd(&statL[cp * 128 + sel * 64 + oh * 32 + c32], v);
    }
}

// ---------------------------------------------------------------------------
// Final: out[b][c][y][x] = x + bn2(y2); bn2 params computed inline per block.
// ---------------------------------------------------------------------------
__launch_bounds__(256)
__global__ void final_kernel(const void* __restrict__ xin,
                             const float* __restrict__ yt2,   // padded
                             const float* __restrict__ statL,
                             const void* __restrict__ gamma, const void* __restrict__ beta,
                             const void* __restrict__ w1,
                             void* __restrict__ outp) {
    __shared__ float tile[64 * 33];
    __shared__ float scL[64], shL[64];
    const int is32 = detect_is32((const unsigned short*)w1);
    if (threadIdx.x < 64) {
        int c = threadIdx.x;
        float s = 0.f, ss = 0.f;
        #pragma unroll
        for (int cp = 0; cp < 8; ++cp) {
            s  += statL[cp * 128 + c];
            ss += statL[cp * 128 + 64 + c];
        }
        float mean = s * (1.f / (float)NPC);
        float var  = fmaxf(ss * (1.f / (float)NPC) - mean * mean, 0.f);
        float inv  = rsqrtf(var + 1e-5f);
        float g = load_in(gamma, c, is32) * inv;
        scL[c] = g;
        shL[c] = load_in(beta, c, is32) - mean * g;
    }
    __syncthreads();

    int x0 = blockIdx.x * 32, y = blockIdx.y, b = blockIdx.z;
    for (int e = threadIdx.x; e < 2048; e += 256) {
        int c = e & 63, xl = e >> 6;
        float v = yt2[((b * PDIM + y + 1) * PDIM + x0 + 1 + xl) * 64 + c];
        tile[c * 33 + xl] = v * scL[c] + shL[c];
    }
    __syncthreads();
    for (int f = threadIdx.x; f < 2048; f += 256) {
        int xl = f & 31, c = f >> 5;
        int idx = ((b * 64 + c) * 96 + y) * 96 + x0 + xl;
        float v = load_in(xin, idx, is32) + tile[c * 33 + xl];
        if (is32) ((float*)outp)[idx] = v;
        else      ((__hip_bfloat16*)outp)[idx] = __float2bfloat16(v);
    }
}

// ---------------------------------------------------------------------------
extern "C" void kernel_launch(void* const* d_in, const int* in_sizes, int n_in,
                              void* d_out, int out_size, void* d_ws, size_t ws_size,
                              hipStream_t stream) {
    const void* x  = d_in[0];
    const void* w1 = d_in[1];
    const void* g1 = d_in[2];
    const void* b1 = d_in[3];
    const void* w2 = d_in[4];
    const void* g2 = d_in[5];
    const void* b2 = d_in[6];

    float* ws    = (float*)d_ws;
    float* bufA  = ws;                  // xt (padded, layer1 in) / yt2 (padded; xt dead by caps2)
    float* bufB  = bufA + PELEM;        // yt1 (padded)
    float* wT1   = bufB + PELEM;        // 36864
    float* wT2   = wT1 + 36864;         // 36864
    float* bias1 = wT2 + 36864;         // 4608 (zeros)
    float* bias2 = bias1 + 4608;        // 4608
    float* statz = bias2 + 4608;        // 2048
    float* statL1 = statz;
    float* statL2 = statz + 1024;

    prep_kernel<<<885, 256, 0, stream>>>(x, w1, w2, bufA, wT1, wT2, statz, bias1);

    dim3 cgrid(24, 96, 2);   // (x-group of 8) x (o-half), rows, batch
    caps_kernel<<<cgrid, 256, 0, stream>>>(bufA, wT1, bias1, bufB, statL1);
    fold_kernel<<<194, 256, 0, stream>>>(statL1, g1, b1, w1, w2, wT2, bias2, bufB);
    caps_kernel<<<cgrid, 256, 0, stream>>>(bufB, wT2, bias2, bufA, statL2);
    final_kernel<<<dim3(3, 96, 2), 256, 0, stream>>>(x, bufA, statL2, g2, b2, w1, d_out);
}